// Round 4
// baseline (20109.251 us; speedup 1.0000x reference)
//
#include <hip/hip_runtime.h>
#include <hip/hip_bf16.h>
#include <math.h>

#define BB   32
#define SS   128
#define DD   64
#define HH   4
#define HDD  16
#define HTT  256
#define TEE  1024
#define NTHR 1024
#define KVSTR 68            // K/V row stride in scratch (64+4)
#define VOFF  (SS * KVSTR)  // V region offset inside scratch (8704 floats)
#define MSTR 132            // mlp half row stride (128+4)
#define STEPF 0.1f

// ---------------------------------------------------------------------------
// Kernel 1: precompute temb[t][d] for all t (shared across batches).
// ---------------------------------------------------------------------------
__global__ void temb_precompute(const int* __restrict__ nloops_p,
                                const float* __restrict__ t_w1,
                                const float* __restrict__ t_b1,
                                const float* __restrict__ t_w2,
                                const float* __restrict__ t_b2,
                                float* __restrict__ tembBuf) {
    const int t = blockIdx.x;
    const int nl = nloops_p[0];
    if (t >= nl) return;

    __shared__ float te_s[HTT];
    __shared__ float h1[TEE];
    const int tid = threadIdx.x;
    const float tf = (float)t;

    {
        int fi = (tid < 128) ? tid : (tid - 128);
        float freq = expf(-9.210340371976184f * (float)fi * (1.0f / 128.0f));
        float arg = tf * freq;
        te_s[tid] = (tid < 128) ? cosf(arg) : sinf(arg);
    }
    __syncthreads();

    for (int j = tid; j < TEE; j += 256) {
        float acc = t_b1[j];
        for (int i = 0; i < HTT; ++i) {
            acc = fmaf(te_s[i], t_w1[i * TEE + j], acc);
        }
        h1[j] = acc / (1.0f + expf(-acc));   // silu
    }
    __syncthreads();

    {
        const int d = tid >> 2;        // 0..63
        const int part = tid & 3;      // 0..3
        float acc = 0.0f;
        for (int j = part; j < TEE; j += 4) {
            acc = fmaf(h1[j], t_w2[j * DD + d], acc);
        }
        acc += __shfl_xor(acc, 1);
        acc += __shfl_xor(acc, 2);
        if (part == 0) tembBuf[t * DD + d] = acc + t_b2[d];
    }
}

// ---------------------------------------------------------------------------
// GELU (tanh approximation, matches jax.nn.gelu approximate=True)
// ---------------------------------------------------------------------------
__device__ __forceinline__ float gelu_tanh(float u) {
    float z = 0.7978845608028654f * (u + 0.044715f * u * u * u);
    float e = __expf(2.0f * z);
    float th = 1.0f - 2.0f / (e + 1.0f);   // tanh(z), inf-safe
    return 0.5f * u * (1.0f + th);
}

// ---------------------------------------------------------------------------
// Kernel 2: whole looped transformer, one block (1024 thr / 16 waves) per batch.
// LDS: xs 32KB (state) + hs 32KB (LN-out / Q / attn-out)
//      + scratch 68KB (K,V / mlp-half)  = 132KB total
// ---------------------------------------------------------------------------
__global__ __launch_bounds__(NTHR)
void looped_tf(const int* __restrict__ idx,
               const int* __restrict__ nloops_p,
               const float* __restrict__ wte,
               const float* __restrict__ wpe,
               const float* __restrict__ ln1_g, const float* __restrict__ ln1_b,
               const float* __restrict__ w_qkv, const float* __restrict__ b_qkv,
               const float* __restrict__ w_o,   const float* __restrict__ b_o,
               const float* __restrict__ ln2_g, const float* __restrict__ ln2_b,
               const float* __restrict__ w_fc,  const float* __restrict__ b_fc,
               const float* __restrict__ w_pr,  const float* __restrict__ b_pr,
               const float* __restrict__ lnf_g, const float* __restrict__ lnf_b,
               const float* __restrict__ tembBuf,
               float* __restrict__ out) {
    __shared__ float xs[SS * DD];             // 32 KB state
    __shared__ float hs[SS * DD];             // 32 KB LN-out / Q / attn-out
    __shared__ float scratch[2 * SS * KVSTR]; // 68 KB: K,V or mlp-half

    const int b = blockIdx.x;
    const int tid = threadIdx.x;
    const int nl = nloops_p[0];

    // ------ init: x = wte[idx] + wpe ------
    for (int i = tid; i < SS * DD; i += NTHR) {
        int s = i >> 6;
        xs[i] = wte[idx[b * SS + s] * DD + (i & 63)] + wpe[i];
    }
    __syncthreads();

    // LN mapping: 8 lanes per token, 8 elems each
    const int tok8 = tid >> 3, sub8 = tid & 7;

    auto layer_norm_to = [&](const float* __restrict__ g,
                             const float* __restrict__ be,
                             float* __restrict__ dst) {
        float v[8];
        const float* xp = xs + tok8 * DD + sub8 * 8;
        float s1 = 0.f, s2 = 0.f;
#pragma unroll
        for (int r = 0; r < 2; ++r) {
            float4 f = *(const float4*)(xp + 4 * r);
            v[4*r+0] = f.x; v[4*r+1] = f.y; v[4*r+2] = f.z; v[4*r+3] = f.w;
            s1 += f.x + f.y + f.z + f.w;
            s2 += f.x*f.x + f.y*f.y + f.z*f.z + f.w*f.w;
        }
        s1 += __shfl_xor(s1, 1); s2 += __shfl_xor(s2, 1);
        s1 += __shfl_xor(s1, 2); s2 += __shfl_xor(s2, 2);
        s1 += __shfl_xor(s1, 4); s2 += __shfl_xor(s2, 4);
        float mu = s1 * (1.0f / 64.0f);
        float var = s2 * (1.0f / 64.0f) - mu * mu;
        float rs = rsqrtf(var + 1e-5f);
#pragma unroll
        for (int i = 0; i < 8; ++i) {
            int d2 = sub8 * 8 + i;
            dst[tok8 * DD + d2] = (v[i] - mu) * rs * g[d2] + be[d2];
        }
    };

    for (int t = 0; t < nl; ++t) {
        // ---- A: x += temb[t] ----
        for (int i = tid; i < SS * DD; i += NTHR)
            xs[i] += tembBuf[t * DD + (i & 63)];
        __syncthreads();

        // ---- B: h = LN1(x) -> hs ----
        layer_norm_to(ln1_g, ln1_b, hs);
        __syncthreads();

        // ---- C: qkv = h @ w_qkv + b_qkv  (128x64 @ 64x192) ----
        // Q -> hs (after barrier), K,V -> scratch
        {
            const int jg = tid & 31, tg = tid >> 5;   // 32 col-groups x 32 tok-groups
            const int j0 = jg * 6, t0 = tg * 4;
            float acc[4][6];
#pragma unroll
            for (int a = 0; a < 4; ++a)
#pragma unroll
                for (int c = 0; c < 6; ++c) acc[a][c] = 0.f;
            for (int d = 0; d < DD; ++d) {
                const float* wp = w_qkv + d * 192 + j0;
                float2 w01 = *(const float2*)(wp + 0);
                float2 w23 = *(const float2*)(wp + 2);
                float2 w45 = *(const float2*)(wp + 4);
                float w[6] = {w01.x, w01.y, w23.x, w23.y, w45.x, w45.y};
#pragma unroll
                for (int a = 0; a < 4; ++a) {
                    float hv = hs[(t0 + a) * DD + d];
#pragma unroll
                    for (int c = 0; c < 6; ++c)
                        acc[a][c] = fmaf(hv, w[c], acc[a][c]);
                }
            }
            __syncthreads();   // all reads of h done before Q overwrites hs
#pragma unroll
            for (int a = 0; a < 4; ++a) {
#pragma unroll
                for (int c = 0; c < 6; ++c) {
                    int col = j0 + c;
                    float v = acc[a][c] + b_qkv[col];
                    if (col < 64)
                        hs[(t0 + a) * DD + col] = v;                        // Q
                    else if (col < 128)
                        scratch[(t0 + a) * KVSTR + (col - 64)] = v;         // K
                    else
                        scratch[VOFF + (t0 + a) * KVSTR + (col - 128)] = v; // V
                }
            }
        }
        __syncthreads();

        // ---- D: causal attention, 2 threads per (q-row, head), k split by parity ----
        {
            const int q  = tid >> 3;
            const int h  = (tid >> 1) & 3;
            const int kp = tid & 1;
            float qv[16];
            const float* qp = hs + q * DD + h * HDD;
#pragma unroll
            for (int r = 0; r < 4; ++r) {
                float4 f = *(const float4*)(qp + 4 * r);
                qv[4*r+0] = f.x; qv[4*r+1] = f.y; qv[4*r+2] = f.z; qv[4*r+3] = f.w;
            }
            float mrun = -3.0e38f, l = 0.f;
            float acc[16];
#pragma unroll
            for (int i = 0; i < 16; ++i) acc[i] = 0.f;
            for (int kk = kp; kk <= q; kk += 2) {
                const float* kptr = scratch + kk * KVSTR + h * HDD;
                const float* vptr = scratch + VOFF + kk * KVSTR + h * HDD;
                float s = 0.f;
                float vv[16];
#pragma unroll
                for (int r = 0; r < 4; ++r) {
                    float4 kf = *(const float4*)(kptr + 4 * r);
                    float4 vf = *(const float4*)(vptr + 4 * r);
                    s = fmaf(qv[4*r+0], kf.x, s);
                    s = fmaf(qv[4*r+1], kf.y, s);
                    s = fmaf(qv[4*r+2], kf.z, s);
                    s = fmaf(qv[4*r+3], kf.w, s);
                    vv[4*r+0] = vf.x; vv[4*r+1] = vf.y; vv[4*r+2] = vf.z; vv[4*r+3] = vf.w;
                }
                s *= 0.25f;   // 1/sqrt(16)
                float mn = fmaxf(mrun, s);
                float corr = __expf(mrun - mn);
                float p = __expf(s - mn);
                l = fmaf(l, corr, p);
#pragma unroll
                for (int i = 0; i < 16; ++i)
                    acc[i] = fmaf(acc[i], corr, p * vv[i]);
                mrun = mn;
            }
            // merge with partner lane (lane^1, same wave, wave-synchronous)
            float mo = __shfl_xor(mrun, 1);
            float lo = __shfl_xor(l, 1);
            float mstar = fmaxf(mrun, mo);
            float cS = __expf(mrun - mstar);   // empty partial: exp(-3e38-m*) = 0
            float cO = __expf(mo - mstar);
            float lstar = fmaf(l, cS, lo * cO);
            float inv = 1.0f / lstar;
#pragma unroll
            for (int i = 0; i < 16; ++i) {
                float ao = __shfl_xor(acc[i], 1);
                acc[i] = (acc[i] * cS + ao * cO) * inv;
            }
            if (kp == 0) {
#pragma unroll
                for (int i = 0; i < 16; ++i)
                    hs[q * DD + h * HDD + i] = acc[i];
            }
        }
        __syncthreads();

        // ---- E: x += STEP * (a @ w_o + b_o) ----
        {
            const int dg = tid & 15, tg = tid >> 4;  // 16 col-groups x 64 tok-groups
            const int d0 = dg * 4, t0 = tg * 2;
            float acc[2][4];
#pragma unroll
            for (int a = 0; a < 2; ++a)
#pragma unroll
                for (int c = 0; c < 4; ++c) acc[a][c] = 0.f;
            for (int dd = 0; dd < DD; ++dd) {
                float4 w = *(const float4*)(w_o + dd * DD + d0);
#pragma unroll
                for (int a = 0; a < 2; ++a) {
                    float av = hs[(t0 + a) * DD + dd];
                    acc[a][0] = fmaf(av, w.x, acc[a][0]);
                    acc[a][1] = fmaf(av, w.y, acc[a][1]);
                    acc[a][2] = fmaf(av, w.z, acc[a][2]);
                    acc[a][3] = fmaf(av, w.w, acc[a][3]);
                }
            }
            float4 bo = *(const float4*)(b_o + d0);
#pragma unroll
            for (int a = 0; a < 2; ++a) {
                xs[(t0+a)*DD + d0+0] += STEPF * (acc[a][0] + bo.x);
                xs[(t0+a)*DD + d0+1] += STEPF * (acc[a][1] + bo.y);
                xs[(t0+a)*DD + d0+2] += STEPF * (acc[a][2] + bo.z);
                xs[(t0+a)*DD + d0+3] += STEPF * (acc[a][3] + bo.w);
            }
        }
        __syncthreads();

        // ---- F: h2 = LN2(x) -> hs ----
        layer_norm_to(ln2_g, ln2_b, hs);
        __syncthreads();

        // ---- G/H: MLP (two 128-col halves of fc share scratch) ----
        {
            const int dgP = tid & 15, tgP = tid >> 4;
            const int d0P = dgP * 4, t0P = tgP * 2;
            float pracc[2][4];
#pragma unroll
            for (int a = 0; a < 2; ++a)
#pragma unroll
                for (int c = 0; c < 4; ++c) pracc[a][c] = 0.f;

#pragma unroll
            for (int hf = 0; hf < 2; ++hf) {
                {
                    const int jg = tid & 31, tg = tid >> 5; // 32 col-groups x 32 tok-groups
                    const int j0 = jg * 4, t0 = tg * 4;
                    float acc[4][4];
#pragma unroll
                    for (int a = 0; a < 4; ++a)
#pragma unroll
                        for (int c = 0; c < 4; ++c) acc[a][c] = 0.f;
                    for (int d = 0; d < DD; ++d) {
                        float4 w = *(const float4*)(w_fc + d * 256 + hf * 128 + j0);
#pragma unroll
                        for (int a = 0; a < 4; ++a) {
                            float hv = hs[(t0 + a) * DD + d];
                            acc[a][0] = fmaf(hv, w.x, acc[a][0]);
                            acc[a][1] = fmaf(hv, w.y, acc[a][1]);
                            acc[a][2] = fmaf(hv, w.z, acc[a][2]);
                            acc[a][3] = fmaf(hv, w.w, acc[a][3]);
                        }
                    }
                    float4 bf = *(const float4*)(b_fc + hf * 128 + j0);
#pragma unroll
                    for (int a = 0; a < 4; ++a) {
                        scratch[(t0+a)*MSTR + j0+0] = gelu_tanh(acc[a][0] + bf.x);
                        scratch[(t0+a)*MSTR + j0+1] = gelu_tanh(acc[a][1] + bf.y);
                        scratch[(t0+a)*MSTR + j0+2] = gelu_tanh(acc[a][2] + bf.z);
                        scratch[(t0+a)*MSTR + j0+3] = gelu_tanh(acc[a][3] + bf.w);
                    }
                }
                __syncthreads();
                for (int j = 0; j < 128; ++j) {
                    float4 w = *(const float4*)(w_pr + (hf * 128 + j) * DD + d0P);
#pragma unroll
                    for (int a = 0; a < 2; ++a) {
                        float mv = scratch[(t0P + a) * MSTR + j];
                        pracc[a][0] = fmaf(mv, w.x, pracc[a][0]);
                        pracc[a][1] = fmaf(mv, w.y, pracc[a][1]);
                        pracc[a][2] = fmaf(mv, w.z, pracc[a][2]);
                        pracc[a][3] = fmaf(mv, w.w, pracc[a][3]);
                    }
                }
                __syncthreads();   // before next half overwrites scratch
            }
            float4 bp = *(const float4*)(b_pr + d0P);
#pragma unroll
            for (int a = 0; a < 2; ++a) {
                xs[(t0P+a)*DD + d0P+0] += STEPF * (pracc[a][0] + bp.x);
                xs[(t0P+a)*DD + d0P+1] += STEPF * (pracc[a][1] + bp.y);
                xs[(t0P+a)*DD + d0P+2] += STEPF * (pracc[a][2] + bp.z);
                xs[(t0P+a)*DD + d0P+3] += STEPF * (pracc[a][3] + bp.w);
            }
        }
        __syncthreads();   // xs stable before next iteration
    }

    // ---- final LN -> out ----
    layer_norm_to(lnf_g, lnf_b, out + b * SS * DD);
}

// ---------------------------------------------------------------------------
extern "C" void kernel_launch(void* const* d_in, const int* in_sizes, int n_in,
                              void* d_out, int out_size, void* d_ws, size_t ws_size,
                              hipStream_t stream) {
    const int*   idx    = (const int*)  d_in[0];
    const int*   nloops = (const int*)  d_in[1];
    const float* wte    = (const float*)d_in[2];
    const float* wpe    = (const float*)d_in[3];
    const float* t_w1   = (const float*)d_in[4];
    const float* t_b1   = (const float*)d_in[5];
    const float* t_w2   = (const float*)d_in[6];
    const float* t_b2   = (const float*)d_in[7];
    const float* ln1_g  = (const float*)d_in[8];
    const float* ln1_b  = (const float*)d_in[9];
    const float* w_qkv  = (const float*)d_in[10];
    const float* b_qkv  = (const float*)d_in[11];
    const float* w_o    = (const float*)d_in[12];
    const float* b_o    = (const float*)d_in[13];
    const float* ln2_g  = (const float*)d_in[14];
    const float* ln2_b  = (const float*)d_in[15];
    const float* w_fc   = (const float*)d_in[16];
    const float* b_fc   = (const float*)d_in[17];
    const float* w_pr   = (const float*)d_in[18];
    const float* b_pr   = (const float*)d_in[19];
    const float* lnf_g  = (const float*)d_in[20];
    const float* lnf_b  = (const float*)d_in[21];

    float* tembBuf = (float*)d_ws;   // 128*64 floats used

    temb_precompute<<<128, 256, 0, stream>>>(nloops, t_w1, t_b1, t_w2, t_b2, tembBuf);
    looped_tf<<<BB, NTHR, 0, stream>>>(idx, nloops, wte, wpe, ln1_g, ln1_b,
                                       w_qkv, b_qkv, w_o, b_o, ln2_g, ln2_b,
                                       w_fc, b_fc, w_pr, b_pr, lnf_g, lnf_b,
                                       tembBuf, (float*)d_out);
}

// Round 5
// 7044.419 us; speedup vs baseline: 2.8546x; 2.8546x over previous
//
#include <hip/hip_runtime.h>
#include <hip/hip_bf16.h>
#include <math.h>

#define BB   32
#define SS   128
#define DD   64
#define HTT  256
#define TEE  1024
#define NTHR 512
#define XSTR 72             // xs row stride (f32), breaks pow2 bank pattern
#define QKVSTR 68           // Q/K/V row stride (f32)
#define STEPF 0.1f

typedef __attribute__((ext_vector_type(8))) short short8b;   // 8 x bf16 (4 VGPR)
typedef __attribute__((ext_vector_type(4))) float float4v;   // MFMA C/D

__device__ __forceinline__ unsigned short f2b(float f) {     // f32 -> bf16 RNE
    union { float f; unsigned int u; } x; x.f = f;
    unsigned int u = x.u + 0x7FFFu + ((x.u >> 16) & 1u);
    return (unsigned short)(u >> 16);
}

// ---------------------------------------------------------------------------
// Kernel 0: pack weights into MFMA B-fragment order, bf16.
// B-frag (16x16x32): lane l, elem e -> B[k = ks*32 + (l>>4)*8 + e][col = nt*16 + (l&15)]
// tiles: qkv 12nt x 2ks (0..23) | o 4x2 (24..31) | fc 16x2 (32..63) | pr 4nt x 8ks (64..95)
// ---------------------------------------------------------------------------
__global__ void pack_frags(const float* __restrict__ w_qkv,
                           const float* __restrict__ w_o,
                           const float* __restrict__ w_fc,
                           const float* __restrict__ w_pr,
                           unsigned short* __restrict__ frags) {
    const int tile = blockIdx.x;
    const int t = threadIdx.x;          // 512
    const int lane = t >> 3, e = t & 7;
    const float* W; int N, nt, ks;
    if (tile < 24)      { W = w_qkv; N = 192; int s = tile;      nt = s >> 1; ks = s & 1; }
    else if (tile < 32) { W = w_o;   N = 64;  int s = tile - 24; nt = s >> 1; ks = s & 1; }
    else if (tile < 64) { W = w_fc;  N = 256; int s = tile - 32; nt = s >> 1; ks = s & 1; }
    else                { W = w_pr;  N = 64;  int s = tile - 64; nt = s >> 3; ks = s & 7; }
    const int k   = ks * 32 + (lane >> 4) * 8 + e;
    const int col = nt * 16 + (lane & 15);
    frags[tile * 512 + lane * 8 + e] = f2b(W[k * N + col]);
}

// ---------------------------------------------------------------------------
// Kernel 1: precompute temb[t][d] for all t (f32, unchanged from round 3).
// ---------------------------------------------------------------------------
__global__ void temb_precompute(const int* __restrict__ nloops_p,
                                const float* __restrict__ t_w1,
                                const float* __restrict__ t_b1,
                                const float* __restrict__ t_w2,
                                const float* __restrict__ t_b2,
                                float* __restrict__ tembBuf) {
    const int t = blockIdx.x;
    const int nl = nloops_p[0];
    if (t >= nl) return;

    __shared__ float te_s[HTT];
    __shared__ float h1[TEE];
    const int tid = threadIdx.x;
    const float tf = (float)t;

    {
        int fi = (tid < 128) ? tid : (tid - 128);
        float freq = expf(-9.210340371976184f * (float)fi * (1.0f / 128.0f));
        float arg = tf * freq;
        te_s[tid] = (tid < 128) ? cosf(arg) : sinf(arg);
    }
    __syncthreads();

    for (int j = tid; j < TEE; j += 256) {
        float acc = t_b1[j];
        for (int i = 0; i < HTT; ++i)
            acc = fmaf(te_s[i], t_w1[i * TEE + j], acc);
        h1[j] = acc / (1.0f + expf(-acc));   // silu
    }
    __syncthreads();

    {
        const int d = tid >> 2, part = tid & 3;
        float acc = 0.0f;
        for (int j = part; j < TEE; j += 4)
            acc = fmaf(h1[j], t_w2[j * DD + d], acc);
        acc += __shfl_xor(acc, 1);
        acc += __shfl_xor(acc, 2);
        if (part == 0) tembBuf[t * DD + d] = acc + t_b2[d];
    }
}

__device__ __forceinline__ float gelu_tanh(float u) {
    float z = 0.7978845608028654f * (u + 0.044715f * u * u * u);
    float e = __expf(2.0f * z);
    float th = 1.0f - 2.0f / (e + 1.0f);
    return 0.5f * u * (1.0f + th);
}

// ---------------------------------------------------------------------------
// Kernel 2: looped transformer. 1 block (512 thr / 8 waves) per batch.
// GEMMs on MFMA (bf16 in / f32 acc), attention + LN on VALU f32.
// LDS: xs f32 [128][72] 36.9KB | hsb bf16 [128][64] swizzled 16.4KB
//      qvkpool f32 3x[128][68] 104.4KB (aliased by msb bf16 [128][256] swizzled)
// ---------------------------------------------------------------------------
__global__ __launch_bounds__(NTHR, 2)
void looped_tf(const int* __restrict__ idx,
               const int* __restrict__ nloops_p,
               const float* __restrict__ wte,
               const float* __restrict__ wpe,
               const float* __restrict__ ln1_g, const float* __restrict__ ln1_b,
               const float* __restrict__ b_qkv,
               const float* __restrict__ b_o,
               const float* __restrict__ ln2_g, const float* __restrict__ ln2_b,
               const float* __restrict__ b_fc,
               const float* __restrict__ b_pr,
               const float* __restrict__ lnf_g, const float* __restrict__ lnf_b,
               const float* __restrict__ tembBuf,
               const unsigned short* __restrict__ frags,
               float* __restrict__ out) {
    __shared__ __align__(16) float xs[SS * XSTR];
    __shared__ __align__(16) unsigned short hsb[SS * DD];
    __shared__ __align__(16) float qvkpool[3 * SS * QKVSTR];

    float* qs  = qvkpool;
    float* ksm = qvkpool + SS * QKVSTR;
    float* vsm = qvkpool + 2 * SS * QKVSTR;
    unsigned short* msb = (unsigned short*)qvkpool;   // [128][256] bf16, aliases QKV

    const unsigned short* qkvF = frags;
    const unsigned short* oF   = frags + 24 * 512;
    const unsigned short* fcF  = frags + 32 * 512;
    const unsigned short* prF  = frags + 64 * 512;

    const int b   = blockIdx.x;
    const int tid = threadIdx.x;
    const int nl  = nloops_p[0];
    const int wv  = tid >> 6;          // wave id: owns rows 16wv..16wv+15
    const int ln  = tid & 63;
    const int fr  = ln & 15;           // fragment row/col
    const int fq  = ln >> 4;           // fragment quadrant (0..3)

    // ---- init: x = wte[idx] + wpe ----
    for (int i = tid; i < SS * DD; i += NTHR) {
        int s = i >> 6, d = i & 63;
        xs[s * XSTR + d] = wte[idx[b * SS + s] * DD + d] + wpe[i];
    }
    __syncthreads();

    const int tok4 = tid >> 2, sub4 = tid & 3;   // LN mapping: 4 lanes/token

    // LN(xs) -> hsb (bf16, XOR-swizzled)
    auto ln_to_hsb = [&](const float* __restrict__ g, const float* __restrict__ be) {
        float v[16];
        const float* xp = xs + tok4 * XSTR + sub4 * 16;
        float s1 = 0.f, s2 = 0.f;
#pragma unroll
        for (int r = 0; r < 4; ++r) {
            float4 f = *(const float4*)(xp + 4 * r);
            v[4*r+0]=f.x; v[4*r+1]=f.y; v[4*r+2]=f.z; v[4*r+3]=f.w;
            s1 += f.x + f.y + f.z + f.w;
            s2 += f.x*f.x + f.y*f.y + f.z*f.z + f.w*f.w;
        }
        s1 += __shfl_xor(s1, 1); s2 += __shfl_xor(s2, 1);
        s1 += __shfl_xor(s1, 2); s2 += __shfl_xor(s2, 2);
        float mu = s1 * (1.0f / 64.0f);
        float var = s2 * (1.0f / 64.0f) - mu * mu;
        float rs = rsqrtf(var + 1e-5f);
        short8b p0, p1;
#pragma unroll
        for (int i = 0; i < 8; ++i) {
            int d2 = sub4 * 16 + i;
            p0[i] = (short)f2b((v[i] - mu) * rs * g[d2] + be[d2]);
        }
#pragma unroll
        for (int i = 0; i < 8; ++i) {
            int d2 = sub4 * 16 + 8 + i;
            p1[i] = (short)f2b((v[8+i] - mu) * rs * g[d2] + be[d2]);
        }
        const int row = tok4, swz = (row & 7) << 4;
        char* base = (char*)hsb;
        int b0 = row * 128 + sub4 * 32;
        *(short8b*)(base + (b0 ^ swz)) = p0;
        *(short8b*)(base + ((b0 + 16) ^ swz)) = p1;
    };

    // A-fragment load from a swizzled bf16 LDS tile (row stride rsB bytes)
    auto load_afrag = [&](const unsigned short* buf, int rstrideB, int kstep) -> short8b {
        int row = wv * 16 + fr;
        int byte = row * rstrideB + kstep * 64 + fq * 16;
        return *(const short8b*)((const char*)buf + (byte ^ ((row & 7) << 4)));
    };

    for (int t = 0; t < nl; ++t) {
        // ---- A: x += temb[t] ----
        for (int i = tid; i < SS * DD; i += NTHR)
            xs[(i >> 6) * XSTR + (i & 63)] += tembBuf[t * DD + (i & 63)];
        __syncthreads();

        // ---- B: LN1 -> hsb ----
        ln_to_hsb(ln1_g, ln1_b);
        __syncthreads();

        // ---- C: qkv = h @ w_qkv + b  (MFMA), Q/K/V -> f32 LDS ----
        {
            short8b a0 = load_afrag(hsb, 128, 0);
            short8b a1 = load_afrag(hsb, 128, 1);
            float4v acc[12];
#pragma unroll
            for (int nt = 0; nt < 12; ++nt) acc[nt] = (float4v)0.0f;
#pragma unroll
            for (int nt = 0; nt < 12; ++nt) {
                short8b b0 = *(const short8b*)(qkvF + ((nt * 2 + 0) * 64 + ln) * 8);
                short8b b1 = *(const short8b*)(qkvF + ((nt * 2 + 1) * 64 + ln) * 8);
                acc[nt] = __builtin_amdgcn_mfma_f32_16x16x32_bf16(a0, b0, acc[nt], 0, 0, 0);
                acc[nt] = __builtin_amdgcn_mfma_f32_16x16x32_bf16(a1, b1, acc[nt], 0, 0, 0);
            }
#pragma unroll
            for (int nt = 0; nt < 12; ++nt) {
                const int col = nt * 16 + fr;
                const float bias = b_qkv[col];
                float* dst;
                int c;
                if (nt < 4)      { dst = qs;  c = col; }
                else if (nt < 8) { dst = ksm; c = col - 64; }
                else             { dst = vsm; c = col - 128; }
#pragma unroll
                for (int r = 0; r < 4; ++r) {
                    int row = wv * 16 + fq * 4 + r;
                    dst[row * QKVSTR + c] = acc[nt][r] + bias;
                }
            }
        }
        __syncthreads();

        // ---- D: causal attention (VALU f32), one (q,head)/thread -> hsb bf16 ----
        {
            const int q = tid >> 2, h = tid & 3;
            float qv[16];
            const float* qp = qs + q * QKVSTR + h * 16;
#pragma unroll
            for (int r = 0; r < 4; ++r) {
                float4 f = *(const float4*)(qp + 4 * r);
                qv[4*r+0]=f.x; qv[4*r+1]=f.y; qv[4*r+2]=f.z; qv[4*r+3]=f.w;
            }
            float mrun = -3.0e38f, l = 0.f;
            float acc[16];
#pragma unroll
            for (int i = 0; i < 16; ++i) acc[i] = 0.f;
            for (int kk = 0; kk <= q; ++kk) {
                const float* kp = ksm + kk * QKVSTR + h * 16;
                const float* vp = vsm + kk * QKVSTR + h * 16;
                float s = 0.f;
                float vv[16];
#pragma unroll
                for (int r = 0; r < 4; ++r) {
                    float4 kf = *(const float4*)(kp + 4 * r);
                    float4 vf = *(const float4*)(vp + 4 * r);
                    s = fmaf(qv[4*r+0], kf.x, s);
                    s = fmaf(qv[4*r+1], kf.y, s);
                    s = fmaf(qv[4*r+2], kf.z, s);
                    s = fmaf(qv[4*r+3], kf.w, s);
                    vv[4*r+0]=vf.x; vv[4*r+1]=vf.y; vv[4*r+2]=vf.z; vv[4*r+3]=vf.w;
                }
                s *= 0.25f;
                float mn = fmaxf(mrun, s);
                float corr = __expf(mrun - mn);
                float p = __expf(s - mn);
                l = fmaf(l, corr, p);
#pragma unroll
                for (int i = 0; i < 16; ++i)
                    acc[i] = fmaf(acc[i], corr, p * vv[i]);
                mrun = mn;
            }
            float inv = 1.0f / l;
            short8b p0, p1;
#pragma unroll
            for (int i = 0; i < 8; ++i) p0[i] = (short)f2b(acc[i] * inv);
#pragma unroll
            for (int i = 0; i < 8; ++i) p1[i] = (short)f2b(acc[8 + i] * inv);
            const int swz = (q & 7) << 4;
            char* base = (char*)hsb;
            int b0 = q * 128 + h * 32;
            *(short8b*)(base + (b0 ^ swz)) = p0;
            *(short8b*)(base + ((b0 + 16) ^ swz)) = p1;
        }
        __syncthreads();

        // ---- E: x += STEP * (a @ w_o + b_o)  (MFMA) ----
        {
            short8b a0 = load_afrag(hsb, 128, 0);
            short8b a1 = load_afrag(hsb, 128, 1);
            float4v acc[4];
#pragma unroll
            for (int nt = 0; nt < 4; ++nt) acc[nt] = (float4v)0.0f;
#pragma unroll
            for (int nt = 0; nt < 4; ++nt) {
                short8b b0 = *(const short8b*)(oF + ((nt * 2 + 0) * 64 + ln) * 8);
                short8b b1 = *(const short8b*)(oF + ((nt * 2 + 1) * 64 + ln) * 8);
                acc[nt] = __builtin_amdgcn_mfma_f32_16x16x32_bf16(a0, b0, acc[nt], 0, 0, 0);
                acc[nt] = __builtin_amdgcn_mfma_f32_16x16x32_bf16(a1, b1, acc[nt], 0, 0, 0);
            }
#pragma unroll
            for (int nt = 0; nt < 4; ++nt) {
                const int col = nt * 16 + fr;
                const float bias = b_o[col];
#pragma unroll
                for (int r = 0; r < 4; ++r) {
                    int row = wv * 16 + fq * 4 + r;
                    xs[row * XSTR + col] += STEPF * (acc[nt][r] + bias);
                }
            }
        }
        __syncthreads();

        // ---- F: LN2 -> hsb ----
        ln_to_hsb(ln2_g, ln2_b);
        __syncthreads();

        // ---- G: m = gelu(h2 @ w_fc + b_fc) -> msb bf16 (aliases QKV) ----
        {
            short8b a0 = load_afrag(hsb, 128, 0);
            short8b a1 = load_afrag(hsb, 128, 1);
            float4v acc[16];
#pragma unroll
            for (int nt = 0; nt < 16; ++nt) acc[nt] = (float4v)0.0f;
#pragma unroll
            for (int nt = 0; nt < 16; ++nt) {
                short8b b0 = *(const short8b*)(fcF + ((nt * 2 + 0) * 64 + ln) * 8);
                short8b b1 = *(const short8b*)(fcF + ((nt * 2 + 1) * 64 + ln) * 8);
                acc[nt] = __builtin_amdgcn_mfma_f32_16x16x32_bf16(a0, b0, acc[nt], 0, 0, 0);
                acc[nt] = __builtin_amdgcn_mfma_f32_16x16x32_bf16(a1, b1, acc[nt], 0, 0, 0);
            }
            char* base = (char*)msb;
#pragma unroll
            for (int nt = 0; nt < 16; ++nt) {
                const int col = nt * 16 + fr;
                const float bias = b_fc[col];
#pragma unroll
                for (int r = 0; r < 4; ++r) {
                    int row = wv * 16 + fq * 4 + r;
                    int byte = row * 512 + col * 2;
                    *(unsigned short*)(base + (byte ^ ((row & 7) << 4))) =
                        f2b(gelu_tanh(acc[nt][r] + bias));
                }
            }
        }
        __syncthreads();

        // ---- H: x += STEP * (m @ w_pr + b_pr)  (MFMA, K=256) ----
        {
            short8b a[8];
#pragma unroll
            for (int ks2 = 0; ks2 < 8; ++ks2)
                a[ks2] = load_afrag(msb, 512, ks2);
            float4v acc[4];
#pragma unroll
            for (int nt = 0; nt < 4; ++nt) acc[nt] = (float4v)0.0f;
#pragma unroll
            for (int nt = 0; nt < 4; ++nt) {
#pragma unroll
                for (int ks2 = 0; ks2 < 8; ++ks2) {
                    short8b bf = *(const short8b*)(prF + ((nt * 8 + ks2) * 64 + ln) * 8);
                    acc[nt] = __builtin_amdgcn_mfma_f32_16x16x32_bf16(a[ks2], bf, acc[nt], 0, 0, 0);
                }
            }
#pragma unroll
            for (int nt = 0; nt < 4; ++nt) {
                const int col = nt * 16 + fr;
                const float bias = b_pr[col];
#pragma unroll
                for (int r = 0; r < 4; ++r) {
                    int row = wv * 16 + fq * 4 + r;
                    xs[row * XSTR + col] += STEPF * (acc[nt][r] + bias);
                }
            }
        }
        __syncthreads();   // xs stable before next iteration
    }

    // ---- final LN -> out (f32 global) ----
    {
        float v[16];
        const float* xp = xs + tok4 * XSTR + sub4 * 16;
        float s1 = 0.f, s2 = 0.f;
#pragma unroll
        for (int r = 0; r < 4; ++r) {
            float4 f = *(const float4*)(xp + 4 * r);
            v[4*r+0]=f.x; v[4*r+1]=f.y; v[4*r+2]=f.z; v[4*r+3]=f.w;
            s1 += f.x + f.y + f.z + f.w;
            s2 += f.x*f.x + f.y*f.y + f.z*f.z + f.w*f.w;
        }
        s1 += __shfl_xor(s1, 1); s2 += __shfl_xor(s2, 1);
        s1 += __shfl_xor(s1, 2); s2 += __shfl_xor(s2, 2);
        float mu = s1 * (1.0f / 64.0f);
        float var = s2 * (1.0f / 64.0f) - mu * mu;
        float rs = rsqrtf(var + 1e-5f);
        float* op = out + b * SS * DD + tok4 * DD + sub4 * 16;
#pragma unroll
        for (int r = 0; r < 4; ++r) {
            float4 f;
            int d2 = sub4 * 16 + 4 * r;
            f.x = (v[4*r+0] - mu) * rs * lnf_g[d2+0] + lnf_b[d2+0];
            f.y = (v[4*r+1] - mu) * rs * lnf_g[d2+1] + lnf_b[d2+1];
            f.z = (v[4*r+2] - mu) * rs * lnf_g[d2+2] + lnf_b[d2+2];
            f.w = (v[4*r+3] - mu) * rs * lnf_g[d2+3] + lnf_b[d2+3];
            *(float4*)(op + 4 * r) = f;
        }
    }
}

// ---------------------------------------------------------------------------
extern "C" void kernel_launch(void* const* d_in, const int* in_sizes, int n_in,
                              void* d_out, int out_size, void* d_ws, size_t ws_size,
                              hipStream_t stream) {
    const int*   idx    = (const int*)  d_in[0];
    const int*   nloops = (const int*)  d_in[1];
    const float* wte    = (const float*)d_in[2];
    const float* wpe    = (const float*)d_in[3];
    const float* t_w1   = (const float*)d_in[4];
    const float* t_b1   = (const float*)d_in[5];
    const float* t_w2   = (const float*)d_in[6];
    const float* t_b2   = (const float*)d_in[7];
    const float* ln1_g  = (const float*)d_in[8];
    const float* ln1_b  = (const float*)d_in[9];
    const float* w_qkv  = (const float*)d_in[10];
    const float* b_qkv  = (const float*)d_in[11];
    const float* w_o    = (const float*)d_in[12];
    const float* b_o    = (const float*)d_in[13];
    const float* ln2_g  = (const float*)d_in[14];
    const float* ln2_b  = (const float*)d_in[15];
    const float* w_fc   = (const float*)d_in[16];
    const float* b_fc   = (const float*)d_in[17];
    const float* w_pr   = (const float*)d_in[18];
    const float* b_pr   = (const float*)d_in[19];
    const float* lnf_g  = (const float*)d_in[20];
    const float* lnf_b  = (const float*)d_in[21];

    float* tembBuf = (float*)d_ws;                                   // 32 KB
    unsigned short* frags = (unsigned short*)((char*)d_ws + 32768);  // 96 KB

    pack_frags<<<96, 512, 0, stream>>>(w_qkv, w_o, w_fc, w_pr, frags);
    temb_precompute<<<128, 256, 0, stream>>>(nloops, t_w1, t_b1, t_w2, t_b2, tembBuf);
    looped_tf<<<BB, NTHR, 0, stream>>>(idx, nloops, wte, wpe, ln1_g, ln1_b,
                                       b_qkv, b_o, ln2_g, ln2_b,
                                       b_fc, b_pr, lnf_g, lnf_b,
                                       tembBuf, frags, (float*)d_out);
}

// Round 7
// 3837.748 us; speedup vs baseline: 5.2399x; 1.8356x over previous
//
#include <hip/hip_runtime.h>
#include <hip/hip_bf16.h>
#include <math.h>

#define BB   32
#define SS   128
#define DD   64
#define HTT  256
#define TEE  1024
#define NTHR 512
#define XST  68             // xs row stride (f32 elems)
#define STEPF 0.1f

typedef __attribute__((ext_vector_type(8))) short short8b;   // 8 x bf16
typedef __attribute__((ext_vector_type(4))) float float4v;   // MFMA C/D

__device__ __forceinline__ unsigned short f2b(float f) {     // f32 -> bf16 RNE
    union { float f; unsigned int u; } x; x.f = f;
    unsigned int u = x.u + 0x7FFFu + ((x.u >> 16) & 1u);
    return (unsigned short)(u >> 16);
}

// ---------------------------------------------------------------------------
// Kernel 0: pack weights into MFMA B-fragment order, bf16 (as round 5).
// frag f: lane l elem e -> B[k = ks*32 + (l>>4)*8 + e][col = nt*16 + (l&15)]
// qkv f=0..23 (nt*2+ks) | o 24..31 | fc 32..63 | pr 64..95 (nt*8+ks)
// ---------------------------------------------------------------------------
__global__ void pack_frags(const float* __restrict__ w_qkv,
                           const float* __restrict__ w_o,
                           const float* __restrict__ w_fc,
                           const float* __restrict__ w_pr,
                           unsigned short* __restrict__ frags) {
    const int tile = blockIdx.x;
    const int t = threadIdx.x;          // 512
    const int lane = t >> 3, e = t & 7;
    const float* W; int N, nt, ks;
    if (tile < 24)      { W = w_qkv; N = 192; int s = tile;      nt = s >> 1; ks = s & 1; }
    else if (tile < 32) { W = w_o;   N = 64;  int s = tile - 24; nt = s >> 1; ks = s & 1; }
    else if (tile < 64) { W = w_fc;  N = 256; int s = tile - 32; nt = s >> 1; ks = s & 1; }
    else                { W = w_pr;  N = 64;  int s = tile - 64; nt = s >> 3; ks = s & 7; }
    const int k   = ks * 32 + (lane >> 4) * 8 + e;
    const int col = nt * 16 + (lane & 15);
    frags[tile * 512 + lane * 8 + e] = f2b(W[k * N + col]);
}

// ---------------------------------------------------------------------------
// Kernel 1: precompute temb[t][d] (unchanged).
// ---------------------------------------------------------------------------
__global__ void temb_precompute(const int* __restrict__ nloops_p,
                                const float* __restrict__ t_w1,
                                const float* __restrict__ t_b1,
                                const float* __restrict__ t_w2,
                                const float* __restrict__ t_b2,
                                float* __restrict__ tembBuf) {
    const int t = blockIdx.x;
    const int nl = nloops_p[0];
    if (t >= nl) return;

    __shared__ float te_s[HTT];
    __shared__ float h1[TEE];
    const int tid = threadIdx.x;
    const float tf = (float)t;

    {
        int fi = (tid < 128) ? tid : (tid - 128);
        float freq = expf(-9.210340371976184f * (float)fi * (1.0f / 128.0f));
        float arg = tf * freq;
        te_s[tid] = (tid < 128) ? cosf(arg) : sinf(arg);
    }
    __syncthreads();

    for (int j = tid; j < TEE; j += 256) {
        float acc = t_b1[j];
        for (int i = 0; i < HTT; ++i)
            acc = fmaf(te_s[i], t_w1[i * TEE + j], acc);
        h1[j] = acc / (1.0f + expf(-acc));   // silu
    }
    __syncthreads();

    {
        const int d = tid >> 2, part = tid & 3;
        float acc = 0.0f;
        for (int j = part; j < TEE; j += 4)
            acc = fmaf(h1[j], t_w2[j * DD + d], acc);
        acc += __shfl_xor(acc, 1);
        acc += __shfl_xor(acc, 2);
        if (part == 0) tembBuf[t * DD + d] = acc + t_b2[d];
    }
}

__device__ __forceinline__ float gelu_tanh(float u) {
    float z = 0.7978845608028654f * (u + 0.044715f * u * u * u);
    float e = __expf(2.0f * z);
    float th = 1.0f - 2.0f / (e + 1.0f);
    return 0.5f * u * (1.0f + th);
}

// ---------------------------------------------------------------------------
// Kernel 2: looped transformer. 1 block (512 thr / 8 waves) per batch.
// All GEMMs + attention on MFMA. LDS:
//   xs f32 [128][68]                       34816B
//   hsb bf16 [128][64] swizzled            16384B
//   pool: qb[4][128][24] | kb | vtb[4][16][136]  (66560B) aliased by msb [128][256]
//   pstage bf16 per-wave [16][40]          10240B
//   wfrag (qkv+o B-frags parked)           32768B
// ---------------------------------------------------------------------------
__global__ __launch_bounds__(NTHR, 2)
void looped_tf(const int* __restrict__ idx,
               const int* __restrict__ nloops_p,
               const float* __restrict__ wte,
               const float* __restrict__ wpe,
               const float* __restrict__ ln1_g, const float* __restrict__ ln1_b,
               const float* __restrict__ b_qkv,
               const float* __restrict__ b_o,
               const float* __restrict__ ln2_g, const float* __restrict__ ln2_b,
               const float* __restrict__ b_fc,
               const float* __restrict__ b_pr,
               const float* __restrict__ lnf_g, const float* __restrict__ lnf_b,
               const float* __restrict__ tembBuf,
               const unsigned short* __restrict__ frags,
               float* __restrict__ out) {
    __shared__ __align__(16) float xs[SS * XST];
    __shared__ __align__(16) unsigned short hsb[SS * DD];
    __shared__ __align__(16) unsigned char pool[66560];
    __shared__ __align__(16) unsigned short pstage[8 * 640];   // wave: [16][40]
    __shared__ __align__(16) unsigned short wfrag[16384];      // frags 0..31

    unsigned char* qb  = pool;                 // [4][128] rows, stride 48B, XOR swz (row>>3)
    unsigned char* kb  = pool + 24576;         // [4][128] rows, stride 48B
    unsigned char* vtb = pool + 49152;         // [4][16] d-rows, stride 272B (V^T)
    unsigned short* msb = (unsigned short*)pool;  // [128] rows x 512B, XOR swz (row&7)

    const unsigned short* fcF = frags + 32 * 512;
    const unsigned short* prF = frags + 64 * 512;

    const int b   = blockIdx.x;
    const int tid = threadIdx.x;
    const int nl  = nloops_p[0];
    const int wv  = tid >> 6;          // wave id
    const int ln  = tid & 63;
    const int fr  = ln & 15;
    const int fq  = ln >> 4;

    // ---- one-time: park qkv+o frags (32KB) in LDS ----
    for (int i = tid; i < 2048; i += NTHR)
        ((int4*)wfrag)[i] = ((const int4*)frags)[i];

    // ---- init: x = wte[idx] + wpe ----
    for (int i = tid; i < SS * DD; i += NTHR) {
        int s = i >> 6, d = i & 63;
        xs[s * XST + d] = wte[idx[b * SS + s] * DD + d] + wpe[i];
    }
    __syncthreads();

    const int tok4 = tid >> 2, sub4 = tid & 3;

    // LN(xs) -> hsb (bf16, XOR-swizzled, stride 128B)
    auto ln_to_hsb = [&](const float* __restrict__ g, const float* __restrict__ be) {
        float v[16];
        const float* xp = xs + tok4 * XST + sub4 * 16;
        float s1 = 0.f, s2 = 0.f;
#pragma unroll
        for (int r = 0; r < 4; ++r) {
            float4 f = *(const float4*)(xp + 4 * r);
            v[4*r+0]=f.x; v[4*r+1]=f.y; v[4*r+2]=f.z; v[4*r+3]=f.w;
            s1 += f.x + f.y + f.z + f.w;
            s2 += f.x*f.x + f.y*f.y + f.z*f.z + f.w*f.w;
        }
        s1 += __shfl_xor(s1, 1); s2 += __shfl_xor(s2, 1);
        s1 += __shfl_xor(s1, 2); s2 += __shfl_xor(s2, 2);
        float mu = s1 * (1.0f / 64.0f);
        float var = s2 * (1.0f / 64.0f) - mu * mu;
        float rs = rsqrtf(var + 1e-5f);
        short8b p0, p1;
#pragma unroll
        for (int i = 0; i < 8; ++i) {
            int d2 = sub4 * 16 + i;
            p0[i] = (short)f2b((v[i] - mu) * rs * g[d2] + be[d2]);
        }
#pragma unroll
        for (int i = 0; i < 8; ++i) {
            int d2 = sub4 * 16 + 8 + i;
            p1[i] = (short)f2b((v[8+i] - mu) * rs * g[d2] + be[d2]);
        }
        const int row = tok4, swz = (row & 7) << 4;
        char* base = (char*)hsb;
        int b0 = row * 128 + sub4 * 32;
        *(short8b*)(base + (b0 ^ swz)) = p0;
        *(short8b*)(base + ((b0 + 16) ^ swz)) = p1;
    };

    // A-frag from swizzled bf16 LDS tile (contiguous wave rows wv*16+fr)
    auto load_afrag = [&](const unsigned short* buf, int rstrideB, int kstep) -> short8b {
        int row = wv * 16 + fr;
        int byte = row * rstrideB + kstep * 64 + fq * 16;
        return *(const short8b*)((const char*)buf + (byte ^ ((row & 7) << 4)));
    };

    for (int t = 0; t < nl; ++t) {
        // ---- A: x += temb[t] ----
        for (int i = tid; i < SS * DD; i += NTHR)
            xs[(i >> 6) * XST + (i & 63)] += tembBuf[t * DD + (i & 63)];
        __syncthreads();

        // ---- B: LN1 -> hsb ----
        ln_to_hsb(ln1_g, ln1_b);
        __syncthreads();

        // ---- C: qkv = h @ w_qkv + b (MFMA, B-frags from LDS) -> qb/kb/vtb bf16 ----
        {
            short8b a0 = load_afrag(hsb, 128, 0);
            short8b a1 = load_afrag(hsb, 128, 1);
            float4v acc[12];
#pragma unroll
            for (int nt = 0; nt < 12; ++nt) acc[nt] = (float4v)0.0f;
#pragma unroll
            for (int nt = 0; nt < 12; ++nt) {
                short8b b0 = *(const short8b*)(&wfrag[(nt * 2 + 0) * 512 + ln * 8]);
                short8b b1 = *(const short8b*)(&wfrag[(nt * 2 + 1) * 512 + ln * 8]);
                acc[nt] = __builtin_amdgcn_mfma_f32_16x16x32_bf16(a0, b0, acc[nt], 0, 0, 0);
                acc[nt] = __builtin_amdgcn_mfma_f32_16x16x32_bf16(a1, b1, acc[nt], 0, 0, 0);
            }
#pragma unroll
            for (int nt = 0; nt < 12; ++nt) {
                const int col = nt * 16 + fr;
                const float bias = b_qkv[col];
#pragma unroll
                for (int r = 0; r < 4; ++r) {
                    int row = wv * 16 + fq * 4 + r;
                    unsigned short bv = f2b(acc[nt][r] + bias);
                    if (nt < 4) {                       // Q: swizzled by row>>3
                        int h = nt, d = fr;
                        int byte = h * 6144 + row * 48 + d * 2;
                        byte ^= ((row >> 3) & 7) << 4;
                        *(unsigned short*)(qb + byte) = bv;
                    } else if (nt < 8) {                // K
                        int h = nt - 4, d = fr;
                        *(unsigned short*)(kb + h * 6144 + row * 48 + d * 2) = bv;
                    } else {                            // V transposed: [h][d][kk]
                        int h = nt - 8, d = fr;
                        *(unsigned short*)(vtb + h * 4352 + d * 272 + row * 2) = bv;
                    }
                }
            }
        }
        __syncthreads();

        // ---- D: flash attention via MFMA (balanced strided rows q = wv+8j) ----
        {
            // Q A-frags per head (lanes>=32 supply the K-dim zero padding)
            short8b aq[4];
            {
                bool lo = (ln < 32);
#pragma unroll
                for (int h = 0; h < 4; ++h) {
                    short8b z = (short8b)(short)0;
                    if (lo) {
                        int q = wv + 8 * fr;
                        int byte = h * 6144 + q * 48 + (fq & 1) * 16;
                        byte ^= (fr & 7) << 4;          // (q>>3)&7 == fr&7
                        z = *(const short8b*)(qb + byte);
                    }
                    aq[h] = z;
                }
            }
            short8b onesb;
#pragma unroll
            for (int e = 0; e < 8; ++e) onesb[e] = (short)0x3F80;  // bf16 1.0

            float4v o[4], lac[4];
#pragma unroll
            for (int h = 0; h < 4; ++h) { o[h] = (float4v)0.0f; lac[h] = (float4v)0.0f; }

            unsigned short* pst = pstage + wv * 640;    // [16][40]

            for (int ktp = 0; ktp < 4; ++ktp) {
#pragma unroll
                for (int h = 0; h < 4; ++h) {
                    // QK^T for two 16-wide k-tiles
                    short8b bk0 = (short8b)(short)0, bk1 = (short8b)(short)0;
                    if (ln < 32) {
                        int kbase = h * 6144 + (fq & 1) * 16;
                        bk0 = *(const short8b*)(kb + kbase + (ktp * 32 + fr) * 48);
                        bk1 = *(const short8b*)(kb + kbase + (ktp * 32 + 16 + fr) * 48);
                    }
                    float4v s0 = __builtin_amdgcn_mfma_f32_16x16x32_bf16(aq[h], bk0, (float4v)0.0f, 0, 0, 0);
                    float4v s1 = __builtin_amdgcn_mfma_f32_16x16x32_bf16(aq[h], bk1, (float4v)0.0f, 0, 0, 0);
                    // mask + exp -> pstage (rows j, cols = kk-local 0..31)
#pragma unroll
                    for (int r = 0; r < 4; ++r) {
                        int j = 4 * fq + r;
                        int q = wv + 8 * j;
                        int kk0 = ktp * 32 + fr;
                        int kk1 = kk0 + 16;
                        float p0 = (kk0 <= q) ? __expf(s0[r] * 0.25f) : 0.0f;
                        float p1 = (kk1 <= q) ? __expf(s1[r] * 0.25f) : 0.0f;
                        pst[j * 40 + fr]      = f2b(p0);
                        pst[j * 40 + 16 + fr] = f2b(p1);
                    }
                    // P A-frag (full K=32), V^T B-frag, ones B-frag for row-sum
                    short8b ap = *(const short8b*)((const char*)pst + fr * 80 + fq * 16);
                    short8b bv = *(const short8b*)(vtb + h * 4352 + fr * 272 + ktp * 64 + fq * 16);
                    o[h]   = __builtin_amdgcn_mfma_f32_16x16x32_bf16(ap, bv, o[h], 0, 0, 0);
                    lac[h] = __builtin_amdgcn_mfma_f32_16x16x32_bf16(ap, onesb, lac[h], 0, 0, 0);
                }
            }
            // normalize + write O -> hsb (bf16, swizzled)
#pragma unroll
            for (int h = 0; h < 4; ++h) {
#pragma unroll
                for (int r = 0; r < 4; ++r) {
                    int j = 4 * fq + r;
                    int q = wv + 8 * j;
                    float val = o[h][r] / lac[h][r];
                    int byte = (q * 128 + (h * 16 + fr) * 2) ^ ((q & 7) << 4);
                    *(unsigned short*)((char*)hsb + byte) = f2b(val);
                }
            }
        }
        __syncthreads();

        // ---- E: x += STEP * (a @ w_o + b_o)  (MFMA, B-frags from LDS) ----
        {
            short8b a0 = load_afrag(hsb, 128, 0);
            short8b a1 = load_afrag(hsb, 128, 1);
            float4v acc[4];
#pragma unroll
            for (int nt = 0; nt < 4; ++nt) acc[nt] = (float4v)0.0f;
#pragma unroll
            for (int nt = 0; nt < 4; ++nt) {
                short8b b0 = *(const short8b*)(&wfrag[(24 + nt * 2 + 0) * 512 + ln * 8]);
                short8b b1 = *(const short8b*)(&wfrag[(24 + nt * 2 + 1) * 512 + ln * 8]);
                acc[nt] = __builtin_amdgcn_mfma_f32_16x16x32_bf16(a0, b0, acc[nt], 0, 0, 0);
                acc[nt] = __builtin_amdgcn_mfma_f32_16x16x32_bf16(a1, b1, acc[nt], 0, 0, 0);
            }
#pragma unroll
            for (int nt = 0; nt < 4; ++nt) {
                const int col = nt * 16 + fr;
                const float bias = b_o[col];
#pragma unroll
                for (int r = 0; r < 4; ++r) {
                    int row = wv * 16 + fq * 4 + r;
                    xs[row * XST + col] += STEPF * (acc[nt][r] + bias);
                }
            }
        }
        __syncthreads();

        // ---- F: LN2 -> hsb ----
        ln_to_hsb(ln2_g, ln2_b);
        __syncthreads();

        // ---- G: m = gelu(h2 @ w_fc + b_fc) -> msb bf16 (aliases QKV pool) ----
        {
            short8b a0 = load_afrag(hsb, 128, 0);
            short8b a1 = load_afrag(hsb, 128, 1);
            float4v acc[16];
#pragma unroll
            for (int nt = 0; nt < 16; ++nt) acc[nt] = (float4v)0.0f;
#pragma unroll
            for (int half = 0; half < 2; ++half) {
                short8b buf[16];
#pragma unroll
                for (int i = 0; i < 16; ++i)
                    buf[i] = *(const short8b*)(fcF + ((half * 16 + i) * 64 + ln) * 8);
#pragma unroll
                for (int i = 0; i < 8; ++i) {
                    int nt = half * 8 + i;
                    acc[nt] = __builtin_amdgcn_mfma_f32_16x16x32_bf16(a0, buf[2*i],   acc[nt], 0, 0, 0);
                    acc[nt] = __builtin_amdgcn_mfma_f32_16x16x32_bf16(a1, buf[2*i+1], acc[nt], 0, 0, 0);
                }
            }
            char* base = (char*)msb;
#pragma unroll
            for (int nt = 0; nt < 16; ++nt) {
                const int col = nt * 16 + fr;
                const float bias = b_fc[col];
#pragma unroll
                for (int r = 0; r < 4; ++r) {
                    int row = wv * 16 + fq * 4 + r;
                    int byte = row * 512 + col * 2;
                    *(unsigned short*)(base + (byte ^ ((row & 7) << 4))) =
                        f2b(gelu_tanh(acc[nt][r] + bias));
                }
            }
        }
        __syncthreads();

        // ---- H: x += STEP * (m @ w_pr + b_pr)  (MFMA, K=256) ----
        {
            short8b am[8];
#pragma unroll
            for (int ks = 0; ks < 8; ++ks)
                am[ks] = load_afrag(msb, 512, ks);
            float4v acc[4];
#pragma unroll
            for (int nt = 0; nt < 4; ++nt) acc[nt] = (float4v)0.0f;
#pragma unroll
            for (int half = 0; half < 2; ++half) {
                short8b buf[16];
#pragma unroll
                for (int i = 0; i < 16; ++i)
                    buf[i] = *(const short8b*)(prF + ((half * 16 + i) * 64 + ln) * 8);
#pragma unroll
                for (int i = 0; i < 16; ++i) {
                    int nt = half * 2 + (i >> 3);
                    acc[nt] = __builtin_amdgcn_mfma_f32_16x16x32_bf16(am[i & 7], buf[i], acc[nt], 0, 0, 0);
                }
            }
#pragma unroll
            for (int nt = 0; nt < 4; ++nt) {
                const int col = nt * 16 + fr;
                const float bias = b_pr[col];
#pragma unroll
                for (int r = 0; r < 4; ++r) {
                    int row = wv * 16 + fq * 4 + r;
                    xs[row * XST + col] += STEPF * (acc[nt][r] + bias);
                }
            }
        }
        __syncthreads();
    }

    // ---- final LN -> out (f32) ----
    {
        float v[16];
        const float* xp = xs + tok4 * XST + sub4 * 16;
        float s1 = 0.f, s2 = 0.f;
#pragma unroll
        for (int r = 0; r < 4; ++r) {
            float4 f = *(const float4*)(xp + 4 * r);
            v[4*r+0]=f.x; v[4*r+1]=f.y; v[4*r+2]=f.z; v[4*r+3]=f.w;
            s1 += f.x + f.y + f.z + f.w;
            s2 += f.x*f.x + f.y*f.y + f.z*f.z + f.w*f.w;
        }
        s1 += __shfl_xor(s1, 1); s2 += __shfl_xor(s2, 1);
        s1 += __shfl_xor(s1, 2); s2 += __shfl_xor(s2, 2);
        float mu = s1 * (1.0f / 64.0f);
        float var = s2 * (1.0f / 64.0f) - mu * mu;
        float rs = rsqrtf(var + 1e-5f);
        float* op = out + b * SS * DD + tok4 * DD + sub4 * 16;
#pragma unroll
        for (int r = 0; r < 4; ++r) {
            float4 f;
            int d2 = sub4 * 16 + 4 * r;
            f.x = (v[4*r+0] - mu) * rs * lnf_g[d2+0] + lnf_b[d2+0];
            f.y = (v[4*r+1] - mu) * rs * lnf_g[d2+1] + lnf_b[d2+1];
            f.z = (v[4*r+2] - mu) * rs * lnf_g[d2+2] + lnf_b[d2+2];
            f.w = (v[4*r+3] - mu) * rs * lnf_g[d2+3] + lnf_b[d2+3];
            *(float4*)(op + 4 * r) = f;
        }
    }
}

// ---------------------------------------------------------------------------
extern "C" void kernel_launch(void* const* d_in, const int* in_sizes, int n_in,
                              void* d_out, int out_size, void* d_ws, size_t ws_size,
                              hipStream_t stream) {
    const int*   idx    = (const int*)  d_in[0];
    const int*   nloops = (const int*)  d_in[1];
    const float* wte    = (const float*)d_in[2];
    const float* wpe    = (const float*)d_in[3];
    const float* t_w1   = (const float*)d_in[4];
    const float* t_b1   = (const float*)d_in[5];
    const float* t_w2   = (const float*)d_in[6];
    const float* t_b2   = (const float*)d_in[7];
    const float* ln1_g  = (const float*)d_in[8];
    const float* ln1_b  = (const float*)d_in[9];
    const float* w_qkv  = (const float*)d_in[10];
    const float* b_qkv  = (const float*)d_in[11];
    const float* w_o    = (const float*)d_in[12];
    const float* b_o    = (const float*)d_in[13];
    const float* ln2_g  = (const float*)d_in[14];
    const float* ln2_b  = (const float*)d_in[15];
    const float* w_fc   = (const float*)d_in[16];
    const float* b_fc   = (const float*)d_in[17];
    const float* w_pr   = (const float*)d_in[18];
    const float* b_pr   = (const float*)d_in[19];
    const float* lnf_g  = (const float*)d_in[20];
    const float* lnf_b  = (const float*)d_in[21];

    float* tembBuf = (float*)d_ws;                                   // 32 KB
    unsigned short* frags = (unsigned short*)((char*)d_ws + 32768);  // 96 KB

    pack_frags<<<96, 512, 0, stream>>>(w_qkv, w_o, w_fc, w_pr, frags);
    temb_precompute<<<128, 256, 0, stream>>>(nloops, t_w1, t_b1, t_w2, t_b2, tembBuf);
    looped_tf<<<BB, NTHR, 0, stream>>>(idx, nloops, wte, wpe, ln1_g, ln1_b,
                                       b_qkv, b_o, ln2_g, ln2_b,
                                       b_fc, b_pr, lnf_g, lnf_b,
                                       tembBuf, frags, (float*)d_out);
}